// Round 1
// baseline (351.425 us; speedup 1.0000x reference)
//
#include <hip/hip_runtime.h>
#include <hip/hip_fp16.h>
#include <math.h>

#define SDE_B 16384
#define SDE_S 16
#define SDE_STEPS 50
#define SDE_L 128
#define SDE_DT 0.02f
#define SDE_SQRT_DT 0.14142135623730951f
#define SDE_TEMP 20.0f
#define LOG2E 1.44269504088896340736f
#define LN2 0.69314718055994530942f
#define SC2 (2.0f * LOG2E)          /* pre-scale so tanh arg feeds exp2 directly */
#define CT (SDE_TEMP * LOG2E)       /* hazard arg scale */

#if __has_builtin(__builtin_amdgcn_exp2f)
__device__ __forceinline__ float fexp2(float x) { return __builtin_amdgcn_exp2f(x); }
#else
__device__ __forceinline__ float fexp2(float x) { return __exp2f(x); }
#endif

#if __has_builtin(__builtin_amdgcn_logf)
__device__ __forceinline__ float flog2(float x) { return __builtin_amdgcn_logf(x); }
#else
__device__ __forceinline__ float flog2(float x) { return __log2f(x); }
#endif

#if __has_builtin(__builtin_amdgcn_rcpf)
__device__ __forceinline__ float frcp(float x) { return __builtin_amdgcn_rcpf(x); }
#else
__device__ __forceinline__ float frcp(float x) { return 1.0f / x; }
#endif

#if __has_builtin(__builtin_amdgcn_fmed3f)
__device__ __forceinline__ float fmed3(float x, float lo, float hi) {
    return __builtin_amdgcn_fmed3f(x, lo, hi);
}
#else
__device__ __forceinline__ float fmed3(float x, float lo, float hi) {
    return fminf(fmaxf(x, lo), hi);
}
#endif

// wave-uniform float -> SGPR
__device__ __forceinline__ float uni(float v) {
#if __has_builtin(__builtin_amdgcn_readfirstlane)
    return __int_as_float(__builtin_amdgcn_readfirstlane(__float_as_int(v)));
#else
    return v;
#endif
}

// extract one f16 from a half2 as float; constant `hi` folds; feeding fmaf()
// lets clang form v_fma_mix_f32 (full-rate, no cvt inst).
__device__ __forceinline__ float hsel(__half2 h, int hi) {
    return __half2float(hi ? __high2half(h) : __low2half(h));
}

// stable softplus: max(y,0) + log(1+exp(-|y|))
__device__ __forceinline__ float softplus_fast(float y) {
    float m = fmaxf(y, 0.0f);
    float e = fexp2(-fabsf(y) * LOG2E);
    return fmaf(LN2, flog2(1.0f + e), m);
}

// sum over the 4-lane quad (lanes grouped as sim*4+q) via DPP quad_perm
__device__ __forceinline__ float quad_sum(float v) {
#if __has_builtin(__builtin_amdgcn_mov_dpp)
    int i = __float_as_int(v);
    v += __int_as_float(__builtin_amdgcn_mov_dpp(i, 0xB1, 0xF, 0xF, true)); // xor 1
    i = __float_as_int(v);
    v += __int_as_float(__builtin_amdgcn_mov_dpp(i, 0x4E, 0xF, 0xF, true)); // xor 2
    return v;
#else
    v += __shfl_xor(v, 1, 64);
    v += __shfl_xor(v, 2, 64);
    return v;
#endif
}

__device__ __forceinline__ float fixnum(float v) {
    if (isnan(v)) return 0.0f;
    if (isinf(v)) return v > 0.0f ? 3.4028234663852886e38f : -3.4028234663852886e38f;
    return v;
}

// One wave per batch element b. 64 lanes = 16 sims x 4 hidden-quarters.
// lane = s*4 + q: sim s, hidden units j = 4*i + q, i in [0,16).
// R8: kernel is VALU-issue-bound (VALUBusy ~98%, HBM 1.3%). Replaced the
// shared-reciprocal trick (1 rcp + 9 muls per group of 4 divisions) with
// direct v_rcp_f32 per unit: per R6/R7 A/B trans ops are ~issue-cost on
// gfx950, so 4 rcps (4 instrs) < 1 rcp + 9 muls (10 instrs). Also fused
// surv update (surv -= cross), (softplus+0.1)*sqrt_dt into one fma, and
// int32 noise indexing. tanh(p) = 1 - 2/(1+exp2(p*2log2e)): weights/zw
// pre-scaled, "1 - 2*" folded into w2' = -2*w2, sum(w2) in the
// accumulator base.
__global__ void __launch_bounds__(256) sde_kernel(
    const float* __restrict__ z,  const float* __restrict__ W1,
    const float* __restrict__ b1, const float* __restrict__ W2,
    const float* __restrict__ b2, const float* __restrict__ Wb,
    const float* __restrict__ bb, const float* __restrict__ Wn,
    const float* __restrict__ bn, const float* __restrict__ osc,
    const float* __restrict__ obias, const float* __restrict__ noise,
    float* __restrict__ out)
{
    const int lane = threadIdx.x & 63;
    const int wv = threadIdx.x >> 6;
    const int b = blockIdx.x * 4 + wv;
    const int s = lane >> 2;
    const int q = lane & 3;

    const float* zr = z + (size_t)b * SDE_L;

    // --- setup: lane l computes zW1 entry for hidden unit j = l ---
    float accz = b1[lane];
    {
        const float* wrow = W1 + lane * 130 + 2;
        #pragma unroll
        for (int m = 0; m < SDE_L; m += 2) {
            float2 w = *(const float2*)(wrow + m);
            accz = fmaf(zr[m], w.x, accz);
            accz = fmaf(zr[m + 1], w.y, accz);
        }
    }
    accz *= SC2;   // pre-scaled for exp2-tanh

    // --- boundary / ndt: 128-dot reduced over the wave ---
    float zb0 = zr[2 * lane], zb1 = zr[2 * lane + 1];
    float pb = fmaf(zb0, Wb[2 * lane], zb1 * Wb[2 * lane + 1]);
    float pn = fmaf(zb0, Wn[2 * lane], zb1 * Wn[2 * lane + 1]);
    #pragma unroll
    for (int off = 32; off > 0; off >>= 1) {
        pb += __shfl_xor(pb, off, 64);
        pn += __shfl_xor(pn, off, 64);
    }
    // wave-uniform scalars -> SGPRs
    const float Hh = uni(CT * (0.5f * (softplus_fast(pb + bb[0]) + 0.3f)));
    const float ndt = uni(softplus_fast(pn + bn[0]) + 0.05f);

    // --- pack this lane's 16 hidden units (j = 4i+q) as f16 half2 pairs ---
    __half2 zwh[8], wxh[8], wth[8], wah[8], wbh[8];
    float S2a = 0.0f, S2b = 0.0f;
    #pragma unroll
    for (int p = 0; p < 8; ++p) {
        int j0 = 4 * (2 * p) + q, j1 = 4 * (2 * p + 1) + q;
        float zw0 = __shfl(accz, j0, 64), zw1 = __shfl(accz, j1, 64);
        zwh[p] = __halves2half2(__float2half_rn(zw0), __float2half_rn(zw1));
        float2 wa0 = *(const float2*)(W1 + j0 * 130);  // {w1x, w1t}
        float2 wa1 = *(const float2*)(W1 + j1 * 130);
        wxh[p] = __halves2half2(__float2half_rn(wa0.x * SC2), __float2half_rn(wa1.x * SC2));
        wth[p] = __halves2half2(__float2half_rn(wa0.y * SC2), __float2half_rn(wa1.y * SC2));
        float a0w = W2[j0], a1w = W2[j1];
        float b0w = W2[64 + j0], b1w = W2[64 + j1];
        S2a += a0w + a1w;
        S2b += b0w + b1w;
        wah[p] = __halves2half2(__float2half_rn(-2.0f * a0w), __float2half_rn(-2.0f * a1w));
        wbh[p] = __halves2half2(__float2half_rn(-2.0f * b0w), __float2half_rn(-2.0f * b1w));
    }
    // per-lane accumulator bases: quad-sum over 4 lanes yields b2 + full sums
    const float a0base = fmaf(0.25f, b2[0], S2a);
    const float a1base = fmaf(0.25f, b2[1], S2b);

    // noise addressing: pure int32 offsets (max index ~13.1M < 2^31) so the
    // prefetch stays on saddr + 32-bit voffset addressing
    const int noff = b * SDE_S + s;

    float x = 0.0f, surv = 1.0f, ert = 0.0f, ecorr = 0.0f;
    float t = 0.0f;
    float nz_cur = noise[noff];   // k=0 preload

    for (int k = 0; k < SDE_STEPS; ++k) {
        // prefetch k+1 (consumed next iteration: full iteration of latency cover)
        int kn = (k + 1 < SDE_STEPS) ? k + 1 : k;
        float nz_nxt = noise[kn * (SDE_B * SDE_S) + noff];

        float a0 = a0base, a1 = a1base;
        #pragma unroll
        for (int g = 0; g < 4; ++g) {
            // 4 units: pairs p = 2g (lo,hi), 2g+1 (lo,hi)
            float pr0 = fmaf(x, hsel(wxh[2*g], 0), fmaf(t, hsel(wth[2*g], 0), hsel(zwh[2*g], 0)));
            float pr1 = fmaf(x, hsel(wxh[2*g], 1), fmaf(t, hsel(wth[2*g], 1), hsel(zwh[2*g], 1)));
            float pr2 = fmaf(x, hsel(wxh[2*g+1], 0), fmaf(t, hsel(wth[2*g+1], 0), hsel(zwh[2*g+1], 0)));
            float pr3 = fmaf(x, hsel(wxh[2*g+1], 1), fmaf(t, hsel(wth[2*g+1], 1), hsel(zwh[2*g+1], 1)));
            // direct per-unit reciprocal: trans ~issue-cost on gfx950, so
            // 4x v_rcp_f32 beats 1 rcp + 9 muls of the shared trick
            float g0 = frcp(fexp2(pr0) + 1.0f);
            float g1 = frcp(fexp2(pr1) + 1.0f);
            float g2 = frcp(fexp2(pr2) + 1.0f);
            float g3 = frcp(fexp2(pr3) + 1.0f);
            // h_i = 1 - 2*g_i folded: a += g_i * (-2*w2); base carries sum(w2)
            a0 = fmaf(g0, hsel(wah[2*g], 0), a0);
            a1 = fmaf(g0, hsel(wbh[2*g], 0), a1);
            a0 = fmaf(g1, hsel(wah[2*g], 1), a0);
            a1 = fmaf(g1, hsel(wbh[2*g], 1), a1);
            a0 = fmaf(g2, hsel(wah[2*g+1], 0), a0);
            a1 = fmaf(g2, hsel(wbh[2*g+1], 0), a1);
            a0 = fmaf(g3, hsel(wah[2*g+1], 1), a0);
            a1 = fmaf(g3, hsel(wbh[2*g+1], 1), a1);
        }
        a0 = quad_sum(a0);
        a1 = quad_sum(a1);
        // identical on all 4 lanes of the quad -> state stays consistent
        float drift = fmed3(a0, -5.0f, 5.0f);
        // diff = softplus(a1) + 0.1; fold (sp + 0.1)*sqrt_dt into one fma
        float sp = softplus_fast(a1);
        float diffs = fmaf(sp, SDE_SQRT_DT, 0.1f * SDE_SQRT_DT);
        x = fmaf(drift, SDE_DT, fmaf(diffs, nz_cur, x));
        x = fmed3(x, -10.0f, 10.0f);
        // hz = sigmoid(TEMP*(|x|-half_b)) = 1/(1+exp2(Hh - CT*|x|))
        float e = fexp2(fmaf(fabsf(x), -CT, Hh));
        float hz = fminf(frcp(1.0f + e), 0.99f);
        float cross = surv * hz;
        surv = surv - cross;            // == surv*(1-hz), one instr fewer
        t += SDE_DT;                    // t is now (k+1)*DT
        ert = fmaf(cross, t, ert);
        ecorr += (x > 0.0f) ? cross : 0.0f;
        nz_cur = nz_nxt;
    }

    ert += surv;                    // * (STEPS*DT) = 1.0
    ecorr = fmaf(surv, 0.5f, ecorr);
    float rt = ert + ndt;           // seconds; x1000 applied after stats

    // --- stats over 16 sims (mask quad-redundant copies to q==0) ---
    float sr = (q == 0) ? rt : 0.0f;
    float scr = (q == 0) ? ecorr : 0.0f;
    #pragma unroll
    for (int off = 32; off > 0; off >>= 1) {
        sr += __shfl_xor(sr, off, 64);
        scr += __shfl_xor(scr, off, 64);
    }
    float mean = sr * (1.0f / 16.0f);
    float d = rt - mean;
    float vv = (q == 0) ? d * d : 0.0f;
    #pragma unroll
    for (int off = 32; off > 0; off >>= 1) vv += __shfl_xor(vv, off, 64);

    if (lane == 0) {
        float std_ms = sqrtf(vv * (1.0f / 15.0f)) * 1000.0f + 0.001f;
        float o0 = fmaf(mean * 1000.0f, osc[0], obias[0]);
        float o1 = fmaf(std_ms, osc[1], obias[1]);
        float o2 = fmaf(scr * (1.0f / 16.0f), osc[2], obias[2]);
        out[b * 3 + 0] = fixnum(o0);
        out[b * 3 + 1] = fixnum(o1);
        out[b * 3 + 2] = fixnum(o2);
    }
}

extern "C" void kernel_launch(void* const* d_in, const int* in_sizes, int n_in,
                              void* d_out, int out_size, void* d_ws, size_t ws_size,
                              hipStream_t stream) {
    const float* z     = (const float*)d_in[0];
    const float* W1    = (const float*)d_in[1];
    const float* b1    = (const float*)d_in[2];
    const float* W2    = (const float*)d_in[3];
    const float* b2    = (const float*)d_in[4];
    const float* Wb    = (const float*)d_in[5];
    const float* bb    = (const float*)d_in[6];
    const float* Wn    = (const float*)d_in[7];
    const float* bn    = (const float*)d_in[8];
    const float* osc   = (const float*)d_in[9];
    const float* obias = (const float*)d_in[10];
    const float* noise = (const float*)d_in[11];
    float* out = (float*)d_out;

    dim3 grid(SDE_B / 4), block(256);
    sde_kernel<<<grid, block, 0, stream>>>(z, W1, b1, W2, b2, Wb, bb, Wn, bn,
                                           osc, obias, noise, out);
}

// Round 2
// 310.442 us; speedup vs baseline: 1.1320x; 1.1320x over previous
//
#include <hip/hip_runtime.h>
#include <hip/hip_fp16.h>
#include <math.h>

#define SDE_B 16384
#define SDE_S 16
#define SDE_STEPS 50
#define SDE_L 128
#define SDE_DT 0.02f
#define SDE_SQRT_DT 0.14142135623730951f
#define SDE_TEMP 20.0f
#define LOG2E 1.44269504088896340736f
#define LN2 0.69314718055994530942f
#define SC2 (2.0f * LOG2E)          /* pre-scale so tanh arg feeds exp2 directly */
#define CT (SDE_TEMP * LOG2E)       /* hazard arg scale */

typedef float f32x2 __attribute__((ext_vector_type(2)));

#if __has_builtin(__builtin_amdgcn_exp2f)
__device__ __forceinline__ float fexp2(float x) { return __builtin_amdgcn_exp2f(x); }
#else
__device__ __forceinline__ float fexp2(float x) { return __exp2f(x); }
#endif

#if __has_builtin(__builtin_amdgcn_logf)
__device__ __forceinline__ float flog2(float x) { return __builtin_amdgcn_logf(x); }
#else
__device__ __forceinline__ float flog2(float x) { return __log2f(x); }
#endif

#if __has_builtin(__builtin_amdgcn_rcpf)
__device__ __forceinline__ float frcp(float x) { return __builtin_amdgcn_rcpf(x); }
#else
__device__ __forceinline__ float frcp(float x) { return 1.0f / x; }
#endif

#if __has_builtin(__builtin_amdgcn_fmed3f)
__device__ __forceinline__ float fmed3(float x, float lo, float hi) {
    return __builtin_amdgcn_fmed3f(x, lo, hi);
}
#else
__device__ __forceinline__ float fmed3(float x, float lo, float hi) {
    return fminf(fmaxf(x, lo), hi);
}
#endif

// wave-uniform float -> SGPR
__device__ __forceinline__ float uni(float v) {
#if __has_builtin(__builtin_amdgcn_readfirstlane)
    return __int_as_float(__builtin_amdgcn_readfirstlane(__float_as_int(v)));
#else
    return v;
#endif
}

// stable softplus: max(y,0) + log(1+exp(-|y|))
__device__ __forceinline__ float softplus_fast(float y) {
    float m = fmaxf(y, 0.0f);
    float e = fexp2(-fabsf(y) * LOG2E);
    return fmaf(LN2, flog2(1.0f + e), m);
}

// sum over the 4-lane quad (lanes grouped as sim*4+q) via DPP quad_perm
__device__ __forceinline__ float quad_sum(float v) {
#if __has_builtin(__builtin_amdgcn_mov_dpp)
    int i = __float_as_int(v);
    v += __int_as_float(__builtin_amdgcn_mov_dpp(i, 0xB1, 0xF, 0xF, true)); // xor 1
    i = __float_as_int(v);
    v += __int_as_float(__builtin_amdgcn_mov_dpp(i, 0x4E, 0xF, 0xF, true)); // xor 2
    return v;
#else
    v += __shfl_xor(v, 1, 64);
    v += __shfl_xor(v, 2, 64);
    return v;
#endif
}

__device__ __forceinline__ float fixnum(float v) {
    if (isnan(v)) return 0.0f;
    if (isinf(v)) return v > 0.0f ? 3.4028234663852886e38f : -3.4028234663852886e38f;
    return v;
}

// One wave per batch element b. 64 lanes = 16 sims x 4 hidden-quarters.
// lane = s*4 + q: sim s, hidden units j = 4*i + q, i in [0,16).
// R9: R8's A/B fit showed trans ops are HALF-RATE (~4 cyc), not issue-cost,
// so the remaining lever is the regular-FMA mass. Switched the MLP from
// f16 fma_mix (1 FMA/slot) to f32 register pairs with float2 ext-vector
// arithmetic -> v_pk_fma_f32 / v_pk_add_f32 (2 FMAs per 2-cyc slot, the
// only path to the 157 TF f32 vector rate). Pre-act 32->16, +1.0 16->8,
// accumulate 32->16 issue slots per step. Costs ~+40 VGPR (f32 weights);
// measured occupancy (33%) is far below the 112-VGPR cap so no loss
// expected. Precision improves (weights back to f32).
// tanh(p) = 1 - 2/(1+exp2(p*2log2e)): weights/zw pre-scaled, "1 - 2*"
// folded into w2' = -2*w2, sum(w2) in the accumulator base.
__global__ void __launch_bounds__(256) sde_kernel(
    const float* __restrict__ z,  const float* __restrict__ W1,
    const float* __restrict__ b1, const float* __restrict__ W2,
    const float* __restrict__ b2, const float* __restrict__ Wb,
    const float* __restrict__ bb, const float* __restrict__ Wn,
    const float* __restrict__ bn, const float* __restrict__ osc,
    const float* __restrict__ obias, const float* __restrict__ noise,
    float* __restrict__ out)
{
    const int lane = threadIdx.x & 63;
    const int wv = threadIdx.x >> 6;
    const int b = blockIdx.x * 4 + wv;
    const int s = lane >> 2;
    const int q = lane & 3;

    const float* zr = z + (size_t)b * SDE_L;

    // --- setup: lane l computes zW1 entry for hidden unit j = l ---
    float accz = b1[lane];
    {
        const float* wrow = W1 + lane * 130 + 2;
        #pragma unroll
        for (int m = 0; m < SDE_L; m += 2) {
            float2 w = *(const float2*)(wrow + m);
            accz = fmaf(zr[m], w.x, accz);
            accz = fmaf(zr[m + 1], w.y, accz);
        }
    }
    accz *= SC2;   // pre-scaled for exp2-tanh

    // --- boundary / ndt: 128-dot reduced over the wave ---
    float zb0 = zr[2 * lane], zb1 = zr[2 * lane + 1];
    float pb = fmaf(zb0, Wb[2 * lane], zb1 * Wb[2 * lane + 1]);
    float pn = fmaf(zb0, Wn[2 * lane], zb1 * Wn[2 * lane + 1]);
    #pragma unroll
    for (int off = 32; off > 0; off >>= 1) {
        pb += __shfl_xor(pb, off, 64);
        pn += __shfl_xor(pn, off, 64);
    }
    // wave-uniform scalars -> SGPRs
    const float Hh = uni(CT * (0.5f * (softplus_fast(pb + bb[0]) + 0.3f)));
    const float ndt = uni(softplus_fast(pn + bn[0]) + 0.05f);

    // --- this lane's 16 hidden units (j = 4i+q) as f32 pairs: (i=2p, 2p+1) ---
    f32x2 zw2[8], wx2[8], wt2[8], wa2[8], wb2[8];
    float S2a = 0.0f, S2b = 0.0f;
    #pragma unroll
    for (int p = 0; p < 8; ++p) {
        int j0 = 4 * (2 * p) + q, j1 = 4 * (2 * p + 1) + q;
        zw2[p].x = __shfl(accz, j0, 64);
        zw2[p].y = __shfl(accz, j1, 64);
        float2 wa0 = *(const float2*)(W1 + j0 * 130);  // {w1x, w1t}
        float2 wa1 = *(const float2*)(W1 + j1 * 130);
        wx2[p].x = wa0.x * SC2; wx2[p].y = wa1.x * SC2;
        wt2[p].x = wa0.y * SC2; wt2[p].y = wa1.y * SC2;
        float a0w = W2[j0], a1w = W2[j1];
        float b0w = W2[64 + j0], b1w = W2[64 + j1];
        S2a += a0w + a1w;
        S2b += b0w + b1w;
        wa2[p].x = -2.0f * a0w; wa2[p].y = -2.0f * a1w;
        wb2[p].x = -2.0f * b0w; wb2[p].y = -2.0f * b1w;
    }
    // per-lane accumulator bases: quad-sum over 4 lanes yields b2 + full sums
    const float a0base = fmaf(0.25f, b2[0], S2a);
    const float a1base = fmaf(0.25f, b2[1], S2b);

    // noise addressing: pure int32 offsets (max index ~13.1M < 2^31)
    const int noff = b * SDE_S + s;

    float x = 0.0f, surv = 1.0f, ert = 0.0f, ecorr = 0.0f;
    f32x2 t2 = {0.0f, 0.0f};
    const f32x2 dt2 = {SDE_DT, SDE_DT};
    const f32x2 one2 = {1.0f, 1.0f};
    float nz_cur = noise[noff];   // k=0 preload

    for (int k = 0; k < SDE_STEPS; ++k) {
        // prefetch k+1 (consumed next iteration: full iteration of latency cover)
        int kn = (k + 1 < SDE_STEPS) ? k + 1 : k;
        float nz_nxt = noise[kn * (SDE_B * SDE_S) + noff];

        f32x2 x2; x2.x = x; x2.y = x;
        f32x2 acc0 = {0.0f, 0.0f}, acc1 = {0.0f, 0.0f};
        #pragma unroll
        for (int p = 0; p < 8; ++p) {
            // 2 units per slot: v_pk_fma_f32 chain for pre-activations
            f32x2 pr = x2 * wx2[p] + (t2 * wt2[p] + zw2[p]);
            f32x2 e; e.x = fexp2(pr.x); e.y = fexp2(pr.y);
            f32x2 d = e + one2;                 // v_pk_add_f32
            f32x2 g; g.x = frcp(d.x); g.y = frcp(d.y);
            // h_i = 1 - 2*g_i folded: acc += g*(-2*w2); base carries sum(w2)
            acc0 += g * wa2[p];                 // v_pk_fma_f32
            acc1 += g * wb2[p];                 // v_pk_fma_f32
        }
        float a0 = a0base + (acc0.x + acc0.y);
        float a1 = a1base + (acc1.x + acc1.y);
        a0 = quad_sum(a0);
        a1 = quad_sum(a1);
        // identical on all 4 lanes of the quad -> state stays consistent
        float drift = fmed3(a0, -5.0f, 5.0f);
        // diff = softplus(a1) + 0.1; fold (sp + 0.1)*sqrt_dt into one fma
        float sp = softplus_fast(a1);
        float diffs = fmaf(sp, SDE_SQRT_DT, 0.1f * SDE_SQRT_DT);
        x = fmaf(drift, SDE_DT, fmaf(diffs, nz_cur, x));
        x = fmed3(x, -10.0f, 10.0f);
        // hz = sigmoid(TEMP*(|x|-half_b)) = 1/(1+exp2(Hh - CT*|x|))
        float e = fexp2(fmaf(fabsf(x), -CT, Hh));
        float hz = fminf(frcp(1.0f + e), 0.99f);
        float cross = surv * hz;
        surv = surv - cross;            // == surv*(1-hz)
        t2 += dt2;                      // t2 is now (k+1)*DT in both halves
        ert = fmaf(cross, t2.x, ert);
        ecorr += (x > 0.0f) ? cross : 0.0f;
        nz_cur = nz_nxt;
    }

    ert += surv;                    // * (STEPS*DT) = 1.0
    ecorr = fmaf(surv, 0.5f, ecorr);
    float rt = ert + ndt;           // seconds; x1000 applied after stats

    // --- stats over 16 sims (mask quad-redundant copies to q==0) ---
    float sr = (q == 0) ? rt : 0.0f;
    float scr = (q == 0) ? ecorr : 0.0f;
    #pragma unroll
    for (int off = 32; off > 0; off >>= 1) {
        sr += __shfl_xor(sr, off, 64);
        scr += __shfl_xor(scr, off, 64);
    }
    float mean = sr * (1.0f / 16.0f);
    float d = rt - mean;
    float vv = (q == 0) ? d * d : 0.0f;
    #pragma unroll
    for (int off = 32; off > 0; off >>= 1) vv += __shfl_xor(vv, off, 64);

    if (lane == 0) {
        float std_ms = sqrtf(vv * (1.0f / 15.0f)) * 1000.0f + 0.001f;
        float o0 = fmaf(mean * 1000.0f, osc[0], obias[0]);
        float o1 = fmaf(std_ms, osc[1], obias[1]);
        float o2 = fmaf(scr * (1.0f / 16.0f), osc[2], obias[2]);
        out[b * 3 + 0] = fixnum(o0);
        out[b * 3 + 1] = fixnum(o1);
        out[b * 3 + 2] = fixnum(o2);
    }
}

extern "C" void kernel_launch(void* const* d_in, const int* in_sizes, int n_in,
                              void* d_out, int out_size, void* d_ws, size_t ws_size,
                              hipStream_t stream) {
    const float* z     = (const float*)d_in[0];
    const float* W1    = (const float*)d_in[1];
    const float* b1    = (const float*)d_in[2];
    const float* W2    = (const float*)d_in[3];
    const float* b2    = (const float*)d_in[4];
    const float* Wb    = (const float*)d_in[5];
    const float* bb    = (const float*)d_in[6];
    const float* Wn    = (const float*)d_in[7];
    const float* bn    = (const float*)d_in[8];
    const float* osc   = (const float*)d_in[9];
    const float* obias = (const float*)d_in[10];
    const float* noise = (const float*)d_in[11];
    float* out = (float*)d_out;

    dim3 grid(SDE_B / 4), block(256);
    sde_kernel<<<grid, block, 0, stream>>>(z, W1, b1, W2, b2, Wb, bb, Wn, bn,
                                           osc, obias, noise, out);
}